// Round 1
// baseline (1069.769 us; speedup 1.0000x reference)
//
#include <hip/hip_runtime.h>
#include <stdint.h>

#define SEQ 2048
#define BSZ 4
#define EMB 1024
#define NH  16
#define HD  64
#define BH  (BSZ*NH)        // 64
#define MROWS (SEQ*BSZ)     // 8192

typedef __attribute__((ext_vector_type(8))) short short8;
typedef __attribute__((ext_vector_type(4))) float f32x4;
typedef __attribute__((ext_vector_type(4))) unsigned short us4;

__device__ __forceinline__ unsigned short f2bf(float f) {
  unsigned u = __float_as_uint(f);
  u += 0x7fffu + ((u >> 16) & 1u);          // round-to-nearest-even
  return (unsigned short)(u >> 16);
}

#define GLDS(g, l) __builtin_amdgcn_global_load_lds( \
    (const __attribute__((address_space(1))) void*)(g), \
    (__attribute__((address_space(3))) void*)(l), 16, 0, 0)

// ---------------- f32 -> bf16 convert (vectorized) ----------------
__global__ void k_cvt(const float* __restrict__ in, unsigned short* __restrict__ out, int n4) {
  int i = blockIdx.x * blockDim.x + threadIdx.x;
  int stride = gridDim.x * blockDim.x;
  for (; i < n4; i += stride) {
    float4 v = reinterpret_cast<const float4*>(in)[i];
    us4 o;
    o[0] = f2bf(v.x); o[1] = f2bf(v.y); o[2] = f2bf(v.z); o[3] = f2bf(v.w);
    reinterpret_cast<us4*>(out)[i] = o;
  }
}

// ---------------- 128x128-tile bt GEMM: C = A * B^T (+bias) ----------------
// A [M][K] bf16 row-major, B [N][K] bf16 row-major (K contiguous both).
// MODE 0: outF[row*N+col] = acc + bias[col]   (f32)
// MODE 1: scatter bf16 into Q/K/V [b,h,s,d]  (QKV projection epilogue)
template<int MODE>
__global__ __launch_bounds__(256, 2) void k_gemm_bt(
    const unsigned short* __restrict__ A, const unsigned short* __restrict__ B,
    const float* __restrict__ bias, float* __restrict__ outF,
    unsigned short* __restrict__ qb, unsigned short* __restrict__ kb,
    unsigned short* __restrict__ vb, int M, int N, int K)
{
  __shared__ unsigned short As[128*32];
  __shared__ unsigned short Bs[128*32];
  const int tid  = threadIdx.x;
  const int lane = tid & 63;
  const int wid  = tid >> 6;
  const int wr = wid >> 1, wc = wid & 1;
  const int r0 = blockIdx.y * 128;
  const int c0 = blockIdx.x * 128;
  const int lr = lane & 15;
  const int hi = lane >> 4;

  f32x4 acc[4][4];
  #pragma unroll
  for (int i = 0; i < 4; i++)
    #pragma unroll
    for (int j = 0; j < 4; j++) acc[i][j] = f32x4{0.f,0.f,0.f,0.f};

  const int nk = K >> 5;
  for (int kt = 0; kt < nk; ++kt) {
    #pragma unroll
    for (int j = 0; j < 2; ++j) {
      int e = (wid*2 + j)*512 + lane*8;
      int row = e >> 5, kk = e & 31;
      GLDS(A + (size_t)(r0 + row)*K + kt*32 + kk, &As[(wid*2+j)*512]);
      GLDS(B + (size_t)(c0 + row)*K + kt*32 + kk, &Bs[(wid*2+j)*512]);
    }
    __syncthreads();
    short8 af[4], bf[4];
    #pragma unroll
    for (int i = 0; i < 4; i++) af[i] = *(const short8*)&As[(wr*64 + i*16 + lr)*32 + hi*8];
    #pragma unroll
    for (int j = 0; j < 4; j++) bf[j] = *(const short8*)&Bs[(wc*64 + j*16 + lr)*32 + hi*8];
    #pragma unroll
    for (int i = 0; i < 4; i++)
      #pragma unroll
      for (int j = 0; j < 4; j++)
        acc[i][j] = __builtin_amdgcn_mfma_f32_16x16x32_bf16(af[i], bf[j], acc[i][j], 0, 0, 0);
    __syncthreads();
  }

  #pragma unroll
  for (int i = 0; i < 4; i++) {
    #pragma unroll
    for (int j = 0; j < 4; j++) {
      #pragma unroll
      for (int r = 0; r < 4; r++) {
        int row = r0 + wr*64 + i*16 + hi*4 + r;
        int col = c0 + wc*64 + j*16 + lr;
        float v = acc[i][j][r] + bias[col];
        if (MODE == 0) {
          outF[(size_t)row*N + col] = v;
        } else {
          int s = row >> 2, b = row & 3;
          int which = col >> 10, h = (col >> 6) & 15, d = col & 63;
          unsigned short bvv = f2bf(v);
          unsigned short* dst = (which == 0) ? qb : (which == 1) ? kb : vb;
          dst[((size_t)(b*NH + h)*SEQ + s)*HD + d] = bvv;
        }
      }
    }
  }
}

// ---------------- V [bh][s][d] -> Vt [bh][d][s] ----------------
__global__ void k_transposeV(const unsigned short* __restrict__ V, unsigned short* __restrict__ Vt) {
  __shared__ unsigned short T[64][65];
  const int bh = blockIdx.y;
  const int s0 = blockIdx.x * 64;
  const int t = threadIdx.x;             // 0..255, 16 elems each
  const int e = t * 16;
  {
    const int s = e >> 6, d0 = e & 63;
    short8 v0 = *(const short8*)&V[((size_t)bh*SEQ + s0 + s)*HD + d0];
    short8 v1 = *(const short8*)&V[((size_t)bh*SEQ + s0 + s)*HD + d0 + 8];
    #pragma unroll
    for (int q = 0; q < 8; q++) { T[s][d0+q] = (unsigned short)v0[q]; T[s][d0+8+q] = (unsigned short)v1[q]; }
  }
  __syncthreads();
  {
    const int d = e >> 6, sl = e & 63;
    short8 w0, w1;
    #pragma unroll
    for (int q = 0; q < 8; q++) { w0[q] = (short)T[sl+q][d]; w1[q] = (short)T[sl+8+q][d]; }
    *(short8*)&Vt[((size_t)bh*HD + d)*SEQ + s0 + sl]     = w0;
    *(short8*)&Vt[((size_t)bh*HD + d)*SEQ + s0 + sl + 8] = w1;
  }
}

// ---------------- fused attention: scores -> softmax -> probs out + PV ----------------
// grid (SEQ/16, BH), 512 threads = 8 waves. Wave w owns cols [w*256, w*256+256).
__global__ __launch_bounds__(512, 2) void k_attn(
    const unsigned short* __restrict__ Q, const unsigned short* __restrict__ Kb,
    const unsigned short* __restrict__ Vt, float* __restrict__ P,
    unsigned short* __restrict__ ctx)
{
  __shared__ char smem[66560];
  unsigned short* Plds = (unsigned short*)smem;          // [8][16*256] bf16 = 64 KB
  float* Olds  = (float*)smem;                           // [8][16*64] f32 = 32 KB (aliased, barrier-separated)
  float* mstat = (float*)(smem + 65536);                 // [8][16]
  float* lstat = (float*)(smem + 66048);                 // [8][16]

  const int tid = threadIdx.x;
  const int lane = tid & 63, w = tid >> 6;
  const int lr = lane & 15, hi = lane >> 4;
  const int r0 = blockIdx.x * 16;
  const int bh = blockIdx.y;
  const int c0 = w * 256;
  const size_t qkBase = (size_t)bh * SEQ * HD;

  // Q fragments (rows r0..r0+15, d 0..63 in two K=32 slices)
  short8 aq0 = *(const short8*)&Q[qkBase + (size_t)(r0 + lr)*HD + hi*8];
  short8 aq1 = *(const short8*)&Q[qkBase + (size_t)(r0 + lr)*HD + 32 + hi*8];

  // scores: 16 col-tiles of 16
  f32x4 sc[16];
  #pragma unroll
  for (int ct = 0; ct < 16; ++ct) {
    const unsigned short* kp = &Kb[qkBase + (size_t)(c0 + ct*16 + lr)*HD + hi*8];
    short8 b0 = *(const short8*)kp;
    short8 b1 = *(const short8*)(kp + 32);
    f32x4 z = f32x4{0.f,0.f,0.f,0.f};
    z = __builtin_amdgcn_mfma_f32_16x16x32_bf16(aq0, b0, z, 0, 0, 0);
    z = __builtin_amdgcn_mfma_f32_16x16x32_bf16(aq1, b1, z, 0, 0, 0);
    sc[ct] = z;
  }

  // scale + per-row max (rows hi*4+r)
  float mx[4] = {-1e30f,-1e30f,-1e30f,-1e30f};
  #pragma unroll
  for (int ct = 0; ct < 16; ++ct)
    #pragma unroll
    for (int r = 0; r < 4; r++) { float v = sc[ct][r]*0.125f; sc[ct][r] = v; mx[r] = fmaxf(mx[r], v); }
  #pragma unroll
  for (int m = 8; m >= 1; m >>= 1)
    #pragma unroll
    for (int r = 0; r < 4; r++) mx[r] = fmaxf(mx[r], __shfl_xor(mx[r], m, 16));
  if (lr == 0) {
    #pragma unroll
    for (int r = 0; r < 4; r++) mstat[w*16 + hi*4 + r] = mx[r];
  }
  __syncthreads();
  float fm[4];
  #pragma unroll
  for (int r = 0; r < 4; r++) {
    int row = hi*4 + r;
    float v = mstat[row];
    #pragma unroll
    for (int ww = 1; ww < 8; ++ww) v = fmaxf(v, mstat[ww*16 + row]);
    fm[r] = v;
  }

  // exp + per-row sum
  float sm[4] = {0.f,0.f,0.f,0.f};
  #pragma unroll
  for (int ct = 0; ct < 16; ++ct)
    #pragma unroll
    for (int r = 0; r < 4; r++) { float e = __expf(sc[ct][r] - fm[r]); sc[ct][r] = e; sm[r] += e; }
  #pragma unroll
  for (int m = 8; m >= 1; m >>= 1)
    #pragma unroll
    for (int r = 0; r < 4; r++) sm[r] += __shfl_xor(sm[r], m, 16);
  if (lr == 0) {
    #pragma unroll
    for (int r = 0; r < 4; r++) lstat[w*16 + hi*4 + r] = sm[r];
  }
  __syncthreads();
  float li[4];
  #pragma unroll
  for (int r = 0; r < 4; r++) {
    int row = hi*4 + r;
    float v = 0.f;
    #pragma unroll
    for (int ww = 0; ww < 8; ++ww) v += lstat[ww*16 + row];
    li[r] = 1.0f / v;
  }

  // write probs (f32, required output) + bf16 P into XOR-swizzled LDS
  unsigned short* myP = Plds + w*4096;
  float* pout = P + ((size_t)bh*SEQ + r0)*SEQ + c0;
  #pragma unroll
  for (int ct = 0; ct < 16; ++ct) {
    #pragma unroll
    for (int r = 0; r < 4; r++) {
      int row = hi*4 + r;
      float p = sc[ct][r] * li[r];
      pout[(size_t)row*SEQ + ct*16 + lr] = p;
      int boff = ((row*256 + ct*16 + lr)*2) ^ ((row & 7) << 4);
      *(unsigned short*)((char*)myP + boff) = f2bf(p);
    }
  }

  // PV: o[16 rows][64 d], wave-partial over its 256 cols
  f32x4 o[4];
  #pragma unroll
  for (int d = 0; d < 4; ++d) o[d] = f32x4{0.f,0.f,0.f,0.f};
  const size_t vtBase = (size_t)bh * HD * SEQ;
  #pragma unroll
  for (int s = 0; s < 8; ++s) {
    int boff = ((lr*256 + s*32 + hi*8)*2) ^ ((lr & 7) << 4);
    short8 pa = *(const short8*)((const char*)myP + boff);
    #pragma unroll
    for (int d = 0; d < 4; ++d) {
      short8 vbf = *(const short8*)&Vt[vtBase + (size_t)(d*16 + lr)*SEQ + c0 + s*32 + hi*8];
      o[d] = __builtin_amdgcn_mfma_f32_16x16x32_bf16(pa, vbf, o[d], 0, 0, 0);
    }
  }

  __syncthreads();   // all P reads done before aliased O region is written
  float* myO = Olds + w*1024;
  #pragma unroll
  for (int d = 0; d < 4; ++d)
    #pragma unroll
    for (int r = 0; r < 4; r++)
      myO[(hi*4 + r)*64 + d*16 + lr] = o[d][r];
  __syncthreads();

  // cross-wave reduce + ctx bf16 store [s*B+b][h*64+d]
  const int b = bh >> 4, h = bh & 15;
  #pragma unroll
  for (int q = 0; q < 2; q++) {
    int e = tid*2 + q;
    int row = e >> 6, d = e & 63;
    float s = 0.f;
    #pragma unroll
    for (int ww = 0; ww < 8; ++ww) s += Olds[ww*1024 + row*64 + d];
    ctx[((size_t)(r0 + row)*BSZ + b)*EMB + h*HD + d] = f2bf(s);
  }
}

extern "C" void kernel_launch(void* const* d_in, const int* in_sizes, int n_in,
                              void* d_out, int out_size, void* d_ws, size_t ws_size,
                              hipStream_t stream) {
  const float* x     = (const float*)d_in[0];
  const float* W_in  = (const float*)d_in[1];
  const float* b_in  = (const float*)d_in[2];
  const float* W_out = (const float*)d_in[3];
  const float* b_out = (const float*)d_in[4];
  float* out   = (float*)d_out;
  float* attnP = out + (size_t)MROWS*EMB;

  char* ws = (char*)d_ws;
  size_t off = 0;
  auto alloc = [&](size_t bytes) { char* p = ws + off; off += (bytes + 255) & ~255ULL; return p; };
  unsigned short* Xbf    = (unsigned short*)alloc((size_t)MROWS*EMB*2);
  unsigned short* Winbf  = (unsigned short*)alloc((size_t)3*EMB*EMB*2);
  unsigned short* Woutbf = (unsigned short*)alloc((size_t)EMB*EMB*2);
  unsigned short* Qb  = (unsigned short*)alloc((size_t)BH*SEQ*HD*2);
  unsigned short* Kbf = (unsigned short*)alloc((size_t)BH*SEQ*HD*2);
  unsigned short* Vb  = (unsigned short*)alloc((size_t)BH*SEQ*HD*2);
  unsigned short* Vt  = (unsigned short*)alloc((size_t)BH*SEQ*HD*2);
  unsigned short* ctx = Xbf;   // Xbf dead after QKV GEMM -> reuse

  k_cvt<<<2048, 256, 0, stream>>>(x,     Xbf,    MROWS*EMB/4);
  k_cvt<<<1024, 256, 0, stream>>>(W_in,  Winbf,  3*EMB*EMB/4);
  k_cvt<<<512,  256, 0, stream>>>(W_out, Woutbf, EMB*EMB/4);

  k_gemm_bt<1><<<dim3(3*EMB/128, MROWS/128), 256, 0, stream>>>(
      Xbf, Winbf, b_in, nullptr, Qb, Kbf, Vb, MROWS, 3*EMB, EMB);

  k_transposeV<<<dim3(SEQ/64, BH), 256, 0, stream>>>(Vb, Vt);

  k_attn<<<dim3(SEQ/16, BH), 512, 0, stream>>>(Qb, Kbf, Vt, attnP, ctx);

  k_gemm_bt<0><<<dim3(EMB/128, MROWS/128), 256, 0, stream>>>(
      ctx, Woutbf, b_out, out, nullptr, nullptr, nullptr, MROWS, EMB, EMB);
}

// Round 2
// 706.373 us; speedup vs baseline: 1.5145x; 1.5145x over previous
//
#include <hip/hip_runtime.h>
#include <stdint.h>

#define SEQ 2048
#define BSZ 4
#define EMB 1024
#define NH  16
#define HD  64
#define BH  (BSZ*NH)        // 64
#define MROWS (SEQ*BSZ)     // 8192

typedef __attribute__((ext_vector_type(8))) short short8;
typedef __attribute__((ext_vector_type(4))) float f32x4;
typedef __attribute__((ext_vector_type(4))) unsigned short us4;

__device__ __forceinline__ unsigned short f2bf(float f) {
  unsigned u = __float_as_uint(f);
  u += 0x7fffu + ((u >> 16) & 1u);          // round-to-nearest-even
  return (unsigned short)(u >> 16);
}

#define GLDS(g, l) __builtin_amdgcn_global_load_lds( \
    (const __attribute__((address_space(1))) void*)(g), \
    (__attribute__((address_space(3))) void*)(l), 16, 0, 0)

// ---------------- f32 -> bf16 convert (vectorized) ----------------
__global__ void k_cvt(const float* __restrict__ in, unsigned short* __restrict__ out, int n4) {
  int i = blockIdx.x * blockDim.x + threadIdx.x;
  int stride = gridDim.x * blockDim.x;
  for (; i < n4; i += stride) {
    float4 v = reinterpret_cast<const float4*>(in)[i];
    us4 o;
    o[0] = f2bf(v.x); o[1] = f2bf(v.y); o[2] = f2bf(v.z); o[3] = f2bf(v.w);
    reinterpret_cast<us4*>(out)[i] = o;
  }
}

// ---------------- 128x128-tile bt GEMM: C = A * B^T (+bias) ----------------
template<int MODE>
__global__ __launch_bounds__(256, 2) void k_gemm_bt(
    const unsigned short* __restrict__ A, const unsigned short* __restrict__ B,
    const float* __restrict__ bias, float* __restrict__ outF,
    unsigned short* __restrict__ qb, unsigned short* __restrict__ kb,
    unsigned short* __restrict__ vb, int M, int N, int K)
{
  __shared__ unsigned short As[128*32];
  __shared__ unsigned short Bs[128*32];
  const int tid  = threadIdx.x;
  const int lane = tid & 63;
  const int wid  = tid >> 6;
  const int wr = wid >> 1, wc = wid & 1;
  const int r0 = blockIdx.y * 128;
  const int c0 = blockIdx.x * 128;
  const int lr = lane & 15;
  const int hi = lane >> 4;

  f32x4 acc[4][4];
  #pragma unroll
  for (int i = 0; i < 4; i++)
    #pragma unroll
    for (int j = 0; j < 4; j++) acc[i][j] = f32x4{0.f,0.f,0.f,0.f};

  const int nk = K >> 5;
  for (int kt = 0; kt < nk; ++kt) {
    #pragma unroll
    for (int j = 0; j < 2; ++j) {
      int e = (wid*2 + j)*512 + lane*8;
      int row = e >> 5, kk = e & 31;
      GLDS(A + (size_t)(r0 + row)*K + kt*32 + kk, &As[(wid*2+j)*512]);
      GLDS(B + (size_t)(c0 + row)*K + kt*32 + kk, &Bs[(wid*2+j)*512]);
    }
    __syncthreads();
    short8 af[4], bf[4];
    #pragma unroll
    for (int i = 0; i < 4; i++) af[i] = *(const short8*)&As[(wr*64 + i*16 + lr)*32 + hi*8];
    #pragma unroll
    for (int j = 0; j < 4; j++) bf[j] = *(const short8*)&Bs[(wc*64 + j*16 + lr)*32 + hi*8];
    #pragma unroll
    for (int i = 0; i < 4; i++)
      #pragma unroll
      for (int j = 0; j < 4; j++)
        acc[i][j] = __builtin_amdgcn_mfma_f32_16x16x32_bf16(af[i], bf[j], acc[i][j], 0, 0, 0);
    __syncthreads();
  }

  #pragma unroll
  for (int i = 0; i < 4; i++) {
    #pragma unroll
    for (int j = 0; j < 4; j++) {
      #pragma unroll
      for (int r = 0; r < 4; r++) {
        int row = r0 + wr*64 + i*16 + hi*4 + r;
        int col = c0 + wc*64 + j*16 + lr;
        float v = acc[i][j][r] + bias[col];
        if (MODE == 0) {
          outF[(size_t)row*N + col] = v;
        } else {
          int s = row >> 2, b = row & 3;
          int which = col >> 10, h = (col >> 6) & 15, d = col & 63;
          unsigned short bvv = f2bf(v);
          unsigned short* dst = (which == 0) ? qb : (which == 1) ? kb : vb;
          dst[((size_t)(b*NH + h)*SEQ + s)*HD + d] = bvv;
        }
      }
    }
  }
}

// ---------------- V [bh][s][d] -> Vt [bh][d][s] ----------------
__global__ void k_transposeV(const unsigned short* __restrict__ V, unsigned short* __restrict__ Vt) {
  __shared__ unsigned short T[64][65];
  const int bh = blockIdx.y;
  const int s0 = blockIdx.x * 64;
  const int t = threadIdx.x;             // 0..255, 16 elems each
  const int e = t * 16;
  {
    const int s = e >> 6, d0 = e & 63;
    short8 v0 = *(const short8*)&V[((size_t)bh*SEQ + s0 + s)*HD + d0];
    short8 v1 = *(const short8*)&V[((size_t)bh*SEQ + s0 + s)*HD + d0 + 8];
    #pragma unroll
    for (int q = 0; q < 8; q++) { T[s][d0+q] = (unsigned short)v0[q]; T[s][d0+8+q] = (unsigned short)v1[q]; }
  }
  __syncthreads();
  {
    const int d = e >> 6, sl = e & 63;
    short8 w0, w1;
    #pragma unroll
    for (int q = 0; q < 8; q++) { w0[q] = (short)T[sl+q][d]; w1[q] = (short)T[sl+8+q][d]; }
    *(short8*)&Vt[((size_t)bh*HD + d)*SEQ + s0 + sl]     = w0;
    *(short8*)&Vt[((size_t)bh*HD + d)*SEQ + s0 + sl + 8] = w1;
  }
}

// ---------------- fused attention v2: wave-independent two-pass ----------------
// 1024 blocks x 256 threads. Block -> (bh, rb): rows rb*128 + w*32 .. +32 per wave
// (2 groups of 16). Pass 1: l = sum exp(s/8) per row (swapped QK orientation).
// Pass 2: recompute scores, p = exp(s/8)/l -> coalesced float4 P write + bf16
// LDS stage -> PV MFMA. No __syncthreads anywhere.
__global__ __launch_bounds__(256, 4) void k_attn2(
    const unsigned short* __restrict__ Q, const unsigned short* __restrict__ Kb,
    const unsigned short* __restrict__ Vt, float* __restrict__ P,
    unsigned short* __restrict__ ctx)
{
  __shared__ unsigned short Pbuf[4][2][512];   // [wave][group][16 rows x 32 k] bf16

  // XCD swizzle: all 16 row-blocks of a head land on the same XCD (i%8 = bh%8)
  const int i   = blockIdx.x;
  const int lo3 = i & 7;
  const int j   = i >> 3;            // [0,128)
  const int bh  = (j >> 4) * 8 + lo3;
  const int rb  = j & 15;

  const int tid = threadIdx.x;
  const int lane = tid & 63, w = tid >> 6;
  const int lr = lane & 15, hi = lane >> 4;
  const int q0 = rb * 128 + w * 32;
  const size_t qkBase = (size_t)bh * SEQ * HD;
  const size_t vtBase = (size_t)bh * HD * SEQ;

  // Q B-fragments for both 16-row groups (two K=32 slices of d)
  short8 bq[2][2];
  #pragma unroll
  for (int g = 0; g < 2; ++g) {
    bq[g][0] = *(const short8*)&Q[qkBase + (size_t)(q0 + g*16 + lr)*HD + hi*8];
    bq[g][1] = *(const short8*)&Q[qkBase + (size_t)(q0 + g*16 + lr)*HD + 32 + hi*8];
  }

  // ---- pass 1: row sums of exp(s * 1/8) ----
  float lsum[2] = {0.f, 0.f};
  #pragma unroll 4
  for (int ct = 0; ct < 128; ++ct) {
    const unsigned short* kp = &Kb[qkBase + (size_t)(ct*16 + lr)*HD + hi*8];
    short8 ak0 = *(const short8*)kp;
    short8 ak1 = *(const short8*)(kp + 32);
    #pragma unroll
    for (int g = 0; g < 2; ++g) {
      f32x4 z = f32x4{0.f,0.f,0.f,0.f};
      z = __builtin_amdgcn_mfma_f32_16x16x32_bf16(ak0, bq[g][0], z, 0, 0, 0);
      z = __builtin_amdgcn_mfma_f32_16x16x32_bf16(ak1, bq[g][1], z, 0, 0, 0);
      #pragma unroll
      for (int r = 0; r < 4; r++) lsum[g] += __expf(z[r] * 0.125f);
    }
  }
  float li[2];
  #pragma unroll
  for (int g = 0; g < 2; ++g) {
    float v = lsum[g];
    v += __shfl_xor(v, 16);
    v += __shfl_xor(v, 32);
    li[g] = 1.0f / v;          // every lane: 1/l for its row q0+g*16+lr
  }

  // ---- pass 2: recompute, write P, PV accumulate ----
  f32x4 o[2][4];
  #pragma unroll
  for (int g = 0; g < 2; ++g)
    #pragma unroll
    for (int d = 0; d < 4; ++d) o[g][d] = f32x4{0.f,0.f,0.f,0.f};

  float* pout = P + ((size_t)bh*SEQ + q0)*SEQ;

  for (int kt = 0; kt < 64; ++kt) {       // 32 k per iteration
    #pragma unroll
    for (int p = 0; p < 2; ++p) {
      const int ct = kt*2 + p;
      const unsigned short* kp = &Kb[qkBase + (size_t)(ct*16 + lr)*HD + hi*8];
      short8 ak0 = *(const short8*)kp;
      short8 ak1 = *(const short8*)(kp + 32);
      #pragma unroll
      for (int g = 0; g < 2; ++g) {
        f32x4 z = f32x4{0.f,0.f,0.f,0.f};
        z = __builtin_amdgcn_mfma_f32_16x16x32_bf16(ak0, bq[g][0], z, 0, 0, 0);
        z = __builtin_amdgcn_mfma_f32_16x16x32_bf16(ak1, bq[g][1], z, 0, 0, 0);
        f32x4 e;
        us4 pk;
        #pragma unroll
        for (int r = 0; r < 4; r++) {
          float pv = __expf(z[r] * 0.125f) * li[g];
          e[r] = pv;
          pk[r] = f2bf(pv);
        }
        // coalesced float4 P write: row q0+g*16+lr, cols ct*16+hi*4..+3
        *(f32x4*)&pout[(size_t)(g*16 + lr)*SEQ + ct*16 + hi*4] = e;
        // bf16 stage into per-wave LDS tile (XOR-swizzled, 8B chunk)
        int woff = (lr*64 + p*32 + hi*8) ^ ((lr & 3) << 4);
        *(us4*)((char*)&Pbuf[w][g][0] + woff) = pk;
      }
    }
    // read A-frags (P[lr][hi*8..+7]) and do PV
    #pragma unroll
    for (int g = 0; g < 2; ++g) {
      int roff = (lr*64 + hi*16) ^ ((lr & 3) << 4);
      short8 pa = *(const short8*)((const char*)&Pbuf[w][g][0] + roff);
      #pragma unroll
      for (int d = 0; d < 4; ++d) {
        short8 vb = *(const short8*)&Vt[vtBase + (size_t)(d*16 + lr)*SEQ + kt*32 + hi*8];
        o[g][d] = __builtin_amdgcn_mfma_f32_16x16x32_bf16(pa, vb, o[g][d], 0, 0, 0);
      }
    }
  }

  // ---- ctx store: [s*B + b][h*64 + d] bf16 ----
  const int b = bh >> 4, h = bh & 15;
  #pragma unroll
  for (int g = 0; g < 2; ++g)
    #pragma unroll
    for (int d = 0; d < 4; ++d)
      #pragma unroll
      for (int r = 0; r < 4; r++) {
        int s = q0 + g*16 + hi*4 + r;
        ctx[((size_t)s*BSZ + b)*EMB + h*HD + d*16 + lr] = f2bf(o[g][d][r]);
      }
}

extern "C" void kernel_launch(void* const* d_in, const int* in_sizes, int n_in,
                              void* d_out, int out_size, void* d_ws, size_t ws_size,
                              hipStream_t stream) {
  const float* x     = (const float*)d_in[0];
  const float* W_in  = (const float*)d_in[1];
  const float* b_in  = (const float*)d_in[2];
  const float* W_out = (const float*)d_in[3];
  const float* b_out = (const float*)d_in[4];
  float* out   = (float*)d_out;
  float* attnP = out + (size_t)MROWS*EMB;

  char* ws = (char*)d_ws;
  size_t off = 0;
  auto alloc = [&](size_t bytes) { char* p = ws + off; off += (bytes + 255) & ~255ULL; return p; };
  unsigned short* Xbf    = (unsigned short*)alloc((size_t)MROWS*EMB*2);
  unsigned short* Winbf  = (unsigned short*)alloc((size_t)3*EMB*EMB*2);
  unsigned short* Woutbf = (unsigned short*)alloc((size_t)EMB*EMB*2);
  unsigned short* Qb  = (unsigned short*)alloc((size_t)BH*SEQ*HD*2);
  unsigned short* Kbf = (unsigned short*)alloc((size_t)BH*SEQ*HD*2);
  unsigned short* Vb  = (unsigned short*)alloc((size_t)BH*SEQ*HD*2);
  unsigned short* Vt  = (unsigned short*)alloc((size_t)BH*SEQ*HD*2);
  unsigned short* ctx = Xbf;   // Xbf dead after QKV GEMM -> reuse

  k_cvt<<<2048, 256, 0, stream>>>(x,     Xbf,    MROWS*EMB/4);
  k_cvt<<<1024, 256, 0, stream>>>(W_in,  Winbf,  3*EMB*EMB/4);
  k_cvt<<<512,  256, 0, stream>>>(W_out, Woutbf, EMB*EMB/4);

  k_gemm_bt<1><<<dim3(3*EMB/128, MROWS/128), 256, 0, stream>>>(
      Xbf, Winbf, b_in, nullptr, Qb, Kbf, Vb, MROWS, 3*EMB, EMB);

  k_transposeV<<<dim3(SEQ/64, BH), 256, 0, stream>>>(Vb, Vt);

  k_attn2<<<1024, 256, 0, stream>>>(Qb, Kbf, Vt, attnP, ctx);

  k_gemm_bt<0><<<dim3(EMB/128, MROWS/128), 256, 0, stream>>>(
      ctx, Woutbf, b_out, out, nullptr, nullptr, nullptr, MROWS, EMB, EMB);
}

// Round 3
// 492.412 us; speedup vs baseline: 2.1725x; 1.4345x over previous
//
#include <hip/hip_runtime.h>
#include <stdint.h>

#define SEQ 2048
#define BSZ 4
#define EMB 1024
#define NH  16
#define HD  64
#define BH  (BSZ*NH)        // 64
#define MROWS (SEQ*BSZ)     // 8192

typedef __attribute__((ext_vector_type(8))) short short8;
typedef __attribute__((ext_vector_type(4))) float f32x4;
typedef __attribute__((ext_vector_type(4))) unsigned short us4;

__device__ __forceinline__ unsigned short f2bf(float f) {
  unsigned u = __float_as_uint(f);
  u += 0x7fffu + ((u >> 16) & 1u);          // round-to-nearest-even
  return (unsigned short)(u >> 16);
}

#define GLDS(g, l) __builtin_amdgcn_global_load_lds( \
    (const __attribute__((address_space(1))) void*)(g), \
    (__attribute__((address_space(3))) void*)(l), 16, 0, 0)

// ---------------- f32 -> bf16 convert (vectorized) ----------------
__global__ void k_cvt(const float* __restrict__ in, unsigned short* __restrict__ out, int n4) {
  int i = blockIdx.x * blockDim.x + threadIdx.x;
  int stride = gridDim.x * blockDim.x;
  for (; i < n4; i += stride) {
    float4 v = reinterpret_cast<const float4*>(in)[i];
    us4 o;
    o[0] = f2bf(v.x); o[1] = f2bf(v.y); o[2] = f2bf(v.z); o[3] = f2bf(v.w);
    reinterpret_cast<us4*>(out)[i] = o;
  }
}

// ---------------- 128x128-tile bt GEMM: C = A * B^T (+bias) ----------------
template<int MODE>
__global__ __launch_bounds__(256, 2) void k_gemm_bt(
    const unsigned short* __restrict__ A, const unsigned short* __restrict__ B,
    const float* __restrict__ bias, float* __restrict__ outF,
    unsigned short* __restrict__ qb, unsigned short* __restrict__ kb,
    unsigned short* __restrict__ vb, int M, int N, int K)
{
  __shared__ unsigned short As[128*32];
  __shared__ unsigned short Bs[128*32];
  const int tid  = threadIdx.x;
  const int lane = tid & 63;
  const int wid  = tid >> 6;
  const int wr = wid >> 1, wc = wid & 1;
  const int r0 = blockIdx.y * 128;
  const int c0 = blockIdx.x * 128;
  const int lr = lane & 15;
  const int hi = lane >> 4;

  f32x4 acc[4][4];
  #pragma unroll
  for (int i = 0; i < 4; i++)
    #pragma unroll
    for (int j = 0; j < 4; j++) acc[i][j] = f32x4{0.f,0.f,0.f,0.f};

  const int nk = K >> 5;
  for (int kt = 0; kt < nk; ++kt) {
    #pragma unroll
    for (int j = 0; j < 2; ++j) {
      int e = (wid*2 + j)*512 + lane*8;
      int row = e >> 5, kk = e & 31;
      GLDS(A + (size_t)(r0 + row)*K + kt*32 + kk, &As[(wid*2+j)*512]);
      GLDS(B + (size_t)(c0 + row)*K + kt*32 + kk, &Bs[(wid*2+j)*512]);
    }
    __syncthreads();
    short8 af[4], bf[4];
    #pragma unroll
    for (int i = 0; i < 4; i++) af[i] = *(const short8*)&As[(wr*64 + i*16 + lr)*32 + hi*8];
    #pragma unroll
    for (int j = 0; j < 4; j++) bf[j] = *(const short8*)&Bs[(wc*64 + j*16 + lr)*32 + hi*8];
    #pragma unroll
    for (int i = 0; i < 4; i++)
      #pragma unroll
      for (int j = 0; j < 4; j++)
        acc[i][j] = __builtin_amdgcn_mfma_f32_16x16x32_bf16(af[i], bf[j], acc[i][j], 0, 0, 0);
    __syncthreads();
  }

  #pragma unroll
  for (int i = 0; i < 4; i++) {
    #pragma unroll
    for (int j = 0; j < 4; j++) {
      #pragma unroll
      for (int r = 0; r < 4; r++) {
        int row = r0 + wr*64 + i*16 + hi*4 + r;
        int col = c0 + wc*64 + j*16 + lr;
        float v = acc[i][j][r] + bias[col];
        if (MODE == 0) {
          outF[(size_t)row*N + col] = v;
        } else {
          int s = row >> 2, b = row & 3;
          int which = col >> 10, h = (col >> 6) & 15, d = col & 63;
          unsigned short bvv = f2bf(v);
          unsigned short* dst = (which == 0) ? qb : (which == 1) ? kb : vb;
          dst[((size_t)(b*NH + h)*SEQ + s)*HD + d] = bvv;
        }
      }
    }
  }
}

// ---------------- V [bh][s][d] -> Vt [bh][d][s] ----------------
__global__ void k_transposeV(const unsigned short* __restrict__ V, unsigned short* __restrict__ Vt) {
  __shared__ unsigned short T[64][65];
  const int bh = blockIdx.y;
  const int s0 = blockIdx.x * 64;
  const int t = threadIdx.x;             // 0..255, 16 elems each
  const int e = t * 16;
  {
    const int s = e >> 6, d0 = e & 63;
    short8 v0 = *(const short8*)&V[((size_t)bh*SEQ + s0 + s)*HD + d0];
    short8 v1 = *(const short8*)&V[((size_t)bh*SEQ + s0 + s)*HD + d0 + 8];
    #pragma unroll
    for (int q = 0; q < 8; q++) { T[s][d0+q] = (unsigned short)v0[q]; T[s][d0+8+q] = (unsigned short)v1[q]; }
  }
  __syncthreads();
  {
    const int d = e >> 6, sl = e & 63;
    short8 w0, w1;
    #pragma unroll
    for (int q = 0; q < 8; q++) { w0[q] = (short)T[sl+q][d]; w1[q] = (short)T[sl+8+q][d]; }
    *(short8*)&Vt[((size_t)bh*HD + d)*SEQ + s0 + sl]     = w0;
    *(short8*)&Vt[((size_t)bh*HD + d)*SEQ + s0 + sl + 8] = w1;
  }
}

// ---------------- fused attention v3: LDS-shared K/V tiles, two-pass ----------------
// 1024 blocks x 512 threads (8 waves). Block -> (bh, rb); wave w owns q-rows
// q0 = rb*128 + w*16 .. +16 (full rows -> row softmax stays wave-local).
// K/Vt staged in double-buffered XOR-swizzled LDS shared by all 8 waves.
// Pass 1: l = sum exp(s/8). Pass 2: recompute, p -> nontemporal f32 store + PV.
__global__ __launch_bounds__(512, 4) void k_attn3(
    const unsigned short* __restrict__ Q, const unsigned short* __restrict__ Kb,
    const unsigned short* __restrict__ Vt, float* __restrict__ P,
    unsigned short* __restrict__ ctx)
{
  __shared__ unsigned short Ks[2][4096];   // [64 k][64 d] swizzled, 8KB each
  __shared__ unsigned short Vs[2][4096];   // [64 d][64 k] swizzled, 8KB each
  __shared__ unsigned short Pb[8][1024];   // per-wave [16 q][64 k] bf16, 2KB each

  // XCD pinning: all 16 row-blocks of a head share i&7
  const int i   = blockIdx.x;
  const int bh  = ((i >> 3) >> 4) * 8 + (i & 7);
  const int rb  = (i >> 3) & 15;

  const int tid = threadIdx.x;
  const int lane = tid & 63, w = tid >> 6;
  const int lr = lane & 15, hi = lane >> 4;
  const int q0 = rb * 128 + w * 16;
  const size_t qkBase = (size_t)bh * SEQ * HD;
  const size_t vtBase = (size_t)bh * HD * SEQ;

  // staging geometry: thread t fills LDS bytes [t*16, t*16+16) (linear, GLDS
  // requirement); the global source column is pre-swizzled so that LDS holds
  // byte[row*128 + (col2 ^ ((row&7)<<4))] = elem[row][col2/2]
  const int srow = tid >> 3;                                      // 0..63
  const int scol = ((((tid & 7) * 16) ^ ((srow & 7) << 4)) >> 1); // elems, mult of 8
  const int swz  = (lr & 7) << 4;

  #define STG_K(buf, kt) GLDS(Kb + qkBase + (size_t)((kt)*64 + srow)*HD + scol, \
                              (unsigned short*)Ks[buf] + tid*8)
  #define STG_V(buf, kt) GLDS(Vt + vtBase + (size_t)srow*SEQ + (kt)*64 + scol, \
                              (unsigned short*)Vs[buf] + tid*8)

  // Q B-fragments (two K=32 d-slices)
  short8 bq0 = *(const short8*)&Q[qkBase + (size_t)(q0 + lr)*HD + hi*8];
  short8 bq1 = *(const short8*)&Q[qkBase + (size_t)(q0 + lr)*HD + 32 + hi*8];

  // ---- pass 1: row sums of exp(s/8) ----
  STG_K(0, 0);
  __syncthreads();
  float lsum = 0.f;
  for (int kt = 0; kt < 32; ++kt) {
    const int cur = kt & 1;
    if (kt < 31) STG_K(cur ^ 1, kt + 1);
    const char* kbase = (const char*)Ks[cur];
    #pragma unroll
    for (int ct = 0; ct < 4; ++ct) {
      const int rowb = (ct*16 + lr) * 128;
      short8 ak0 = *(const short8*)(kbase + ((rowb + hi*16) ^ swz));
      short8 ak1 = *(const short8*)(kbase + ((rowb + 64 + hi*16) ^ swz));
      f32x4 z = f32x4{0.f,0.f,0.f,0.f};
      z = __builtin_amdgcn_mfma_f32_16x16x32_bf16(ak0, bq0, z, 0, 0, 0);
      z = __builtin_amdgcn_mfma_f32_16x16x32_bf16(ak1, bq1, z, 0, 0, 0);
      lsum += __expf(z[0]*0.125f) + __expf(z[1]*0.125f)
            + __expf(z[2]*0.125f) + __expf(z[3]*0.125f);
    }
    __syncthreads();
  }
  float lv = lsum;
  lv += __shfl_xor(lv, 16);
  lv += __shfl_xor(lv, 32);
  const float li = 1.0f / lv;        // 1/l for row q0+lr

  // ---- pass 2: recompute, write P (nontemporal), PV accumulate ----
  f32x4 o[4];
  #pragma unroll
  for (int d = 0; d < 4; ++d) o[d] = f32x4{0.f,0.f,0.f,0.f};

  float* pout = P + ((size_t)bh*SEQ + q0)*SEQ;
  char* pbw = (char*)Pb[w];

  STG_K(0, 0); STG_V(0, 0);          // Ks[0] disjoint from pass1's last tile (Ks[1])
  __syncthreads();
  for (int kt = 0; kt < 32; ++kt) {
    const int cur = kt & 1;
    if (kt < 31) { STG_K(cur ^ 1, kt + 1); STG_V(cur ^ 1, kt + 1); }
    const char* kbase = (const char*)Ks[cur];
    const char* vbase = (const char*)Vs[cur];
    #pragma unroll
    for (int ct = 0; ct < 4; ++ct) {
      const int rowb = (ct*16 + lr) * 128;
      short8 ak0 = *(const short8*)(kbase + ((rowb + hi*16) ^ swz));
      short8 ak1 = *(const short8*)(kbase + ((rowb + 64 + hi*16) ^ swz));
      f32x4 z = f32x4{0.f,0.f,0.f,0.f};
      z = __builtin_amdgcn_mfma_f32_16x16x32_bf16(ak0, bq0, z, 0, 0, 0);
      z = __builtin_amdgcn_mfma_f32_16x16x32_bf16(ak1, bq1, z, 0, 0, 0);
      f32x4 e; us4 pk;
      #pragma unroll
      for (int r = 0; r < 4; r++) {
        float pv = __expf(z[r]*0.125f) * li;
        e[r] = pv; pk[r] = f2bf(pv);
      }
      __builtin_nontemporal_store(e,
          (f32x4*)&pout[(size_t)lr*SEQ + kt*64 + ct*16 + hi*4]);
      *(us4*)(pbw + ((lr*128 + ct*32 + hi*8) ^ swz)) = pk;
    }
    short8 pa0 = *(const short8*)(pbw + ((lr*128 + hi*16) ^ swz));
    short8 pa1 = *(const short8*)(pbw + ((lr*128 + 64 + hi*16) ^ swz));
    #pragma unroll
    for (int dt = 0; dt < 4; ++dt) {
      const int rowb = (dt*16 + lr) * 128;
      short8 vb0 = *(const short8*)(vbase + ((rowb + hi*16) ^ swz));
      short8 vb1 = *(const short8*)(vbase + ((rowb + 64 + hi*16) ^ swz));
      o[dt] = __builtin_amdgcn_mfma_f32_16x16x32_bf16(pa0, vb0, o[dt], 0, 0, 0);
      o[dt] = __builtin_amdgcn_mfma_f32_16x16x32_bf16(pa1, vb1, o[dt], 0, 0, 0);
    }
    __syncthreads();
  }

  // ---- ctx store: [s*B + b][h*64 + d] bf16 ----
  const int b = bh >> 4, h = bh & 15;
  #pragma unroll
  for (int dt = 0; dt < 4; ++dt)
    #pragma unroll
    for (int r = 0; r < 4; r++) {
      int s = q0 + hi*4 + r;
      ctx[((size_t)s*BSZ + b)*EMB + h*HD + dt*16 + lr] = f2bf(o[dt][r]);
    }
  #undef STG_K
  #undef STG_V
}

extern "C" void kernel_launch(void* const* d_in, const int* in_sizes, int n_in,
                              void* d_out, int out_size, void* d_ws, size_t ws_size,
                              hipStream_t stream) {
  const float* x     = (const float*)d_in[0];
  const float* W_in  = (const float*)d_in[1];
  const float* b_in  = (const float*)d_in[2];
  const float* W_out = (const float*)d_in[3];
  const float* b_out = (const float*)d_in[4];
  float* out   = (float*)d_out;
  float* attnP = out + (size_t)MROWS*EMB;

  char* ws = (char*)d_ws;
  size_t off = 0;
  auto alloc = [&](size_t bytes) { char* p = ws + off; off += (bytes + 255) & ~255ULL; return p; };
  unsigned short* Xbf    = (unsigned short*)alloc((size_t)MROWS*EMB*2);
  unsigned short* Winbf  = (unsigned short*)alloc((size_t)3*EMB*EMB*2);
  unsigned short* Woutbf = (unsigned short*)alloc((size_t)EMB*EMB*2);
  unsigned short* Qb  = (unsigned short*)alloc((size_t)BH*SEQ*HD*2);
  unsigned short* Kbf = (unsigned short*)alloc((size_t)BH*SEQ*HD*2);
  unsigned short* Vb  = (unsigned short*)alloc((size_t)BH*SEQ*HD*2);
  unsigned short* Vt  = (unsigned short*)alloc((size_t)BH*SEQ*HD*2);
  unsigned short* ctx = Xbf;   // Xbf dead after QKV GEMM -> reuse

  k_cvt<<<2048, 256, 0, stream>>>(x,     Xbf,    MROWS*EMB/4);
  k_cvt<<<1024, 256, 0, stream>>>(W_in,  Winbf,  3*EMB*EMB/4);
  k_cvt<<<512,  256, 0, stream>>>(W_out, Woutbf, EMB*EMB/4);

  k_gemm_bt<1><<<dim3(3*EMB/128, MROWS/128), 256, 0, stream>>>(
      Xbf, Winbf, b_in, nullptr, Qb, Kbf, Vb, MROWS, 3*EMB, EMB);

  k_transposeV<<<dim3(SEQ/64, BH), 256, 0, stream>>>(Vb, Vt);

  k_attn3<<<1024, 512, 0, stream>>>(Qb, Kbf, Vt, attnP, ctx);

  k_gemm_bt<0><<<dim3(EMB/128, MROWS/128), 256, 0, stream>>>(
      ctx, Woutbf, b_out, out, nullptr, nullptr, nullptr, MROWS, EMB, EMB);
}

// Round 7
// 367.051 us; speedup vs baseline: 2.9145x; 1.3415x over previous
//
#include <hip/hip_runtime.h>
#include <stdint.h>

#define SEQ 2048
#define BSZ 4
#define EMB 1024
#define NH  16
#define HD  64
#define BH  (BSZ*NH)        // 64
#define MROWS (SEQ*BSZ)     // 8192

typedef __attribute__((ext_vector_type(8))) short short8;
typedef __attribute__((ext_vector_type(4))) float f32x4;
typedef __attribute__((ext_vector_type(4))) unsigned short us4;

__device__ __forceinline__ unsigned short f2bf(float f) {
  unsigned u = __float_as_uint(f);
  u += 0x7fffu + ((u >> 16) & 1u);          // round-to-nearest-even
  return (unsigned short)(u >> 16);
}

#define GLDS(g, l) __builtin_amdgcn_global_load_lds( \
    (const __attribute__((address_space(1))) void*)(g), \
    (__attribute__((address_space(3))) void*)(l), 16, 0, 0)

// ---------------- f32 -> bf16 convert (vectorized) ----------------
__global__ void k_cvt(const float* __restrict__ in, unsigned short* __restrict__ out, int n4) {
  int i = blockIdx.x * blockDim.x + threadIdx.x;
  int stride = gridDim.x * blockDim.x;
  for (; i < n4; i += stride) {
    float4 v = reinterpret_cast<const float4*>(in)[i];
    us4 o;
    o[0] = f2bf(v.x); o[1] = f2bf(v.y); o[2] = f2bf(v.z); o[3] = f2bf(v.w);
    reinterpret_cast<us4*>(out)[i] = o;
  }
}

// ---------------- 128x128-tile bt GEMM: C = A * B^T (+bias) ----------------
template<int MODE>
__global__ __launch_bounds__(256, 2) void k_gemm_bt(
    const unsigned short* __restrict__ A, const unsigned short* __restrict__ B,
    const float* __restrict__ bias, float* __restrict__ outF,
    unsigned short* __restrict__ qb, unsigned short* __restrict__ kb,
    unsigned short* __restrict__ vb, int M, int N, int K)
{
  __shared__ unsigned short As[128*32];
  __shared__ unsigned short Bs[128*32];
  const int tid  = threadIdx.x;
  const int lane = tid & 63;
  const int wid  = tid >> 6;
  const int wr = wid >> 1, wc = wid & 1;
  const int r0 = blockIdx.y * 128;
  const int c0 = blockIdx.x * 128;
  const int lr = lane & 15;
  const int hi = lane >> 4;

  f32x4 acc[4][4];
  #pragma unroll
  for (int i = 0; i < 4; i++)
    #pragma unroll
    for (int j = 0; j < 4; j++) acc[i][j] = f32x4{0.f,0.f,0.f,0.f};

  const int nk = K >> 5;
  for (int kt = 0; kt < nk; ++kt) {
    #pragma unroll
    for (int j = 0; j < 2; ++j) {
      int e = (wid*2 + j)*512 + lane*8;
      int row = e >> 5, kk = e & 31;
      GLDS(A + (size_t)(r0 + row)*K + kt*32 + kk, &As[(wid*2+j)*512]);
      GLDS(B + (size_t)(c0 + row)*K + kt*32 + kk, &Bs[(wid*2+j)*512]);
    }
    __syncthreads();
    short8 af[4], bf[4];
    #pragma unroll
    for (int i = 0; i < 4; i++) af[i] = *(const short8*)&As[(wr*64 + i*16 + lr)*32 + hi*8];
    #pragma unroll
    for (int j = 0; j < 4; j++) bf[j] = *(const short8*)&Bs[(wc*64 + j*16 + lr)*32 + hi*8];
    #pragma unroll
    for (int i = 0; i < 4; i++)
      #pragma unroll
      for (int j = 0; j < 4; j++)
        acc[i][j] = __builtin_amdgcn_mfma_f32_16x16x32_bf16(af[i], bf[j], acc[i][j], 0, 0, 0);
    __syncthreads();
  }

  #pragma unroll
  for (int i = 0; i < 4; i++) {
    #pragma unroll
    for (int j = 0; j < 4; j++) {
      #pragma unroll
      for (int r = 0; r < 4; r++) {
        int row = r0 + wr*64 + i*16 + hi*4 + r;
        int col = c0 + wc*64 + j*16 + lr;
        float v = acc[i][j][r] + bias[col];
        if (MODE == 0) {
          outF[(size_t)row*N + col] = v;
        } else {
          int s = row >> 2, b = row & 3;
          int which = col >> 10, h = (col >> 6) & 15, d = col & 63;
          unsigned short bvv = f2bf(v);
          unsigned short* dst = (which == 0) ? qb : (which == 1) ? kb : vb;
          dst[((size_t)(b*NH + h)*SEQ + s)*HD + d] = bvv;
        }
      }
    }
  }
}

// ---------------- V [bh][s][d] -> Vt [bh][d][s] ----------------
__global__ void k_transposeV(const unsigned short* __restrict__ V, unsigned short* __restrict__ Vt) {
  __shared__ unsigned short T[64][65];
  const int bh = blockIdx.y;
  const int s0 = blockIdx.x * 64;
  const int t = threadIdx.x;             // 0..255, 16 elems each
  const int e = t * 16;
  {
    const int s = e >> 6, d0 = e & 63;
    short8 v0 = *(const short8*)&V[((size_t)bh*SEQ + s0 + s)*HD + d0];
    short8 v1 = *(const short8*)&V[((size_t)bh*SEQ + s0 + s)*HD + d0 + 8];
    #pragma unroll
    for (int q = 0; q < 8; q++) { T[s][d0+q] = (unsigned short)v0[q]; T[s][d0+8+q] = (unsigned short)v1[q]; }
  }
  __syncthreads();
  {
    const int d = e >> 6, sl = e & 63;
    short8 w0, w1;
    #pragma unroll
    for (int q = 0; q < 8; q++) { w0[q] = (short)T[sl+q][d]; w1[q] = (short)T[sl+8+q][d]; }
    *(short8*)&Vt[((size_t)bh*HD + d)*SEQ + s0 + sl]     = w0;
    *(short8*)&Vt[((size_t)bh*HD + d)*SEQ + s0 + sl + 8] = w1;
  }
}

// ---------------- fused attention v5: v4 with CORRECT counted vmcnt ----------------
// Counting discipline: s_waitcnt vmcnt(N) guarantees all but the newest N VMEM
// ops retired -> to require op X complete, N = #ops issued AFTER X.
// Pass 1 (1 GLDS/iter): after issuing G(kt+2), G(kt+1) has 1 newer op -> vmcnt(1).
// Pass 2 (4 NT stores + 2 GLDS/iter): G(kt+1) has 4+2=6 newer -> vmcnt(6);
// prologue K0,V0 have 2 newer (K1,V1) -> vmcnt(2); kt=30 tail -> vmcnt(4).
__global__ __launch_bounds__(512, 4) void k_attn5(
    const unsigned short* __restrict__ Q, const unsigned short* __restrict__ Kb,
    const unsigned short* __restrict__ Vt, float* __restrict__ P,
    unsigned short* __restrict__ ctx)
{
  __shared__ unsigned short Ks[3][4096];   // [64 k][64 d] swizzled, 8KB each
  __shared__ unsigned short Vs[3][4096];   // [64 d][64 k] swizzled, 8KB each
  __shared__ float Pf[8][1024];            // per-wave [16 q][64 k] f32, swizzled

  const int i   = blockIdx.x;
  const int bh  = i & 63;                  // XCD = bh & 7 for all 16 row-blocks
  const int rb  = i >> 6;

  const int tid = threadIdx.x;
  const int lane = tid & 63, w = tid >> 6;
  const int lr = lane & 15, hi = lane >> 4;
  const int q0 = rb * 128 + w * 16;
  const size_t qkBase = (size_t)bh * SEQ * HD;
  const size_t vtBase = (size_t)bh * HD * SEQ;

  // staging: thread t fills LDS bytes [t*16, t*16+16); global col pre-swizzled
  const int srow = tid >> 3;                                      // 0..63
  const int scol = ((((tid & 7) * 16) ^ ((srow & 7) << 4)) >> 1); // elems
  const int swz  = (lr & 7) << 4;

  #define STG_K(buf, kt) GLDS(Kb + qkBase + (size_t)((kt)*64 + srow)*HD + scol, \
                              (unsigned short*)Ks[buf] + tid*8)
  #define STG_V(buf, kt) GLDS(Vt + vtBase + (size_t)srow*SEQ + (kt)*64 + scol, \
                              (unsigned short*)Vs[buf] + tid*8)
  #define WAITV(n) asm volatile("s_waitcnt vmcnt(" #n ")" ::: "memory")
  #define BARRIER __builtin_amdgcn_s_barrier(); asm volatile("" ::: "memory")

  // Q B-fragments (two K=32 d-slices)
  short8 bq0 = *(const short8*)&Q[qkBase + (size_t)(q0 + lr)*HD + hi*8];
  short8 bq1 = *(const short8*)&Q[qkBase + (size_t)(q0 + lr)*HD + 32 + hi*8];

  // ---- pass 1: row sums of exp(s/8) ----
  STG_K(0, 0); STG_K(1, 1);
  WAITV(1);                        // K0 landed (K1 may float)
  BARRIER;
  float lsum = 0.f;
  {
    int cur = 0;
    for (int kt = 0; kt < 32; ++kt) {
      const char* kbase = (const char*)Ks[cur];
      #pragma unroll
      for (int ct = 0; ct < 4; ++ct) {
        const int rowb = (ct*16 + lr) * 128;
        short8 ak0 = *(const short8*)(kbase + ((rowb + hi*16) ^ swz));
        short8 ak1 = *(const short8*)(kbase + ((rowb + 64 + hi*16) ^ swz));
        f32x4 z = f32x4{0.f,0.f,0.f,0.f};
        z = __builtin_amdgcn_mfma_f32_16x16x32_bf16(ak0, bq0, z, 0, 0, 0);
        z = __builtin_amdgcn_mfma_f32_16x16x32_bf16(ak1, bq1, z, 0, 0, 0);
        lsum += __expf(z[0]*0.125f) + __expf(z[1]*0.125f)
              + __expf(z[2]*0.125f) + __expf(z[3]*0.125f);
      }
      int bs = cur + 2; if (bs >= 3) bs -= 3;
      if (kt < 30) {
        STG_K(bs, kt + 2);
        WAITV(1);                  // K(kt+1) landed; K(kt+2) floats
      } else {
        WAITV(0);
      }
      BARRIER;
      cur = (cur >= 2) ? 0 : cur + 1;
    }
  }
  float lv = lsum;
  lv += __shfl_xor(lv, 16);
  lv += __shfl_xor(lv, 32);
  const float li = 1.0f / lv;        // 1/l for row q0+lr

  // ---- pass 2: recompute, staged coalesced P store, PV accumulate ----
  f32x4 o[4];
  #pragma unroll
  for (int d = 0; d < 4; ++d) o[d] = f32x4{0.f,0.f,0.f,0.f};

  float* pout = P + ((size_t)bh*SEQ + q0)*SEQ;
  char* pfw = (char*)Pf[w];

  STG_K(0, 0); STG_V(0, 0); STG_K(1, 1); STG_V(1, 1);
  WAITV(2);                        // K0,V0 landed (K1,V1 float)
  BARRIER;
  {
    int cur = 0;
    for (int kt = 0; kt < 32; ++kt) {
      const char* kbase = (const char*)Ks[cur];
      const char* vbase = (const char*)Vs[cur];
      // QK + exp -> Pf (swizzled f32 tile)
      #pragma unroll
      for (int ct = 0; ct < 4; ++ct) {
        const int rowb = (ct*16 + lr) * 128;
        short8 ak0 = *(const short8*)(kbase + ((rowb + hi*16) ^ swz));
        short8 ak1 = *(const short8*)(kbase + ((rowb + 64 + hi*16) ^ swz));
        f32x4 z = f32x4{0.f,0.f,0.f,0.f};
        z = __builtin_amdgcn_mfma_f32_16x16x32_bf16(ak0, bq0, z, 0, 0, 0);
        z = __builtin_amdgcn_mfma_f32_16x16x32_bf16(ak1, bq1, z, 0, 0, 0);
        f32x4 e;
        #pragma unroll
        for (int r = 0; r < 4; r++) e[r] = __expf(z[r]*0.125f) * li;
        *(f32x4*)(pfw + ((((ct*4 + hi) ^ lr) << 4) + lr*256)) = e;
      }
      // coalesced NT P stores: 4 insts, each 4 rows x 256B
      #pragma unroll
      for (int j = 0; j < 4; ++j) {
        const int row = j*4 + hi;
        f32x4 pv4 = *(const f32x4*)(pfw + (row*256 + ((lr ^ row) << 4)));
        __builtin_nontemporal_store(pv4,
            (f32x4*)&pout[(size_t)row*SEQ + kt*64 + lr*4]);
      }
      // PV: pa frags from Pf (cvt f32->bf16), V frags from Vs
      #pragma unroll
      for (int s = 0; s < 2; ++s) {
        const int c0 = s*8 + hi*2;
        f32x4 f0 = *(const f32x4*)(pfw + (lr*256 + (((c0    ) ^ lr) << 4)));
        f32x4 f1 = *(const f32x4*)(pfw + (lr*256 + (((c0 + 1) ^ lr) << 4)));
        short8 pa;
        #pragma unroll
        for (int r = 0; r < 4; r++) { pa[r] = (short)f2bf(f0[r]); pa[4+r] = (short)f2bf(f1[r]); }
        #pragma unroll
        for (int dt = 0; dt < 4; ++dt) {
          const int rowb = (dt*16 + lr) * 128;
          short8 vb = *(const short8*)(vbase + ((rowb + s*64 + hi*16) ^ swz));
          o[dt] = __builtin_amdgcn_mfma_f32_16x16x32_bf16(pa, vb, o[dt], 0, 0, 0);
        }
      }
      if (kt < 30) {
        int bs = cur + 2; if (bs >= 3) bs -= 3;
        STG_K(bs, kt + 2); STG_V(bs, kt + 2);
        WAITV(6);                  // K/V(kt+1) landed (newer: 4 stores + 2 GLDS)
        BARRIER;
      } else if (kt == 30) {
        WAITV(4);                  // K/V(31) landed (newer: 4 stores)
        BARRIER;
      }
      // kt == 31: nothing reads K/V LDS afterwards -> no wait, no barrier
      cur = (cur >= 2) ? 0 : cur + 1;
    }
  }

  // ---- ctx store: [s*B + b][h*64 + d] bf16 ----
  const int b = bh >> 4, h = bh & 15;
  #pragma unroll
  for (int dt = 0; dt < 4; ++dt)
    #pragma unroll
    for (int r = 0; r < 4; r++) {
      int s = q0 + hi*4 + r;
      ctx[((size_t)s*BSZ + b)*EMB + h*HD + dt*16 + lr] = f2bf(o[dt][r]);
    }
  #undef STG_K
  #undef STG_V
  #undef WAITV
  #undef BARRIER
}

extern "C" void kernel_launch(void* const* d_in, const int* in_sizes, int n_in,
                              void* d_out, int out_size, void* d_ws, size_t ws_size,
                              hipStream_t stream) {
  const float* x     = (const float*)d_in[0];
  const float* W_in  = (const float*)d_in[1];
  const float* b_in  = (const float*)d_in[2];
  const float* W_out = (const float*)d_in[3];
  const float* b_out = (const float*)d_in[4];
  float* out   = (float*)d_out;
  float* attnP = out + (size_t)MROWS*EMB;

  char* ws = (char*)d_ws;
  size_t off = 0;
  auto alloc = [&](size_t bytes) { char* p = ws + off; off += (bytes + 255) & ~255ULL; return p; };
  unsigned short* Xbf    = (unsigned short*)alloc((size_t)MROWS*EMB*2);
  unsigned short* Winbf  = (unsigned short*)alloc((size_t)3*EMB*EMB*2);
  unsigned short* Woutbf = (unsigned short*)alloc((size_t)EMB*EMB*2);
  unsigned short* Qb  = (unsigned short*)alloc((size_t)BH*SEQ*HD*2);
  unsigned short* Kbf = (unsigned short*)alloc((size_t)BH*SEQ*HD*2);
  unsigned short* Vb  = (unsigned short*)alloc((size_t)BH*SEQ*HD*2);
  unsigned short* Vt  = (unsigned short*)alloc((size_t)BH*SEQ*HD*2);
  unsigned short* ctx = Xbf;   // Xbf dead after QKV GEMM -> reuse

  k_cvt<<<2048, 256, 0, stream>>>(x,     Xbf,    MROWS*EMB/4);
  k_cvt<<<1024, 256, 0, stream>>>(W_in,  Winbf,  3*EMB*EMB/4);
  k_cvt<<<512,  256, 0, stream>>>(W_out, Woutbf, EMB*EMB/4);

  k_gemm_bt<1><<<dim3(3*EMB/128, MROWS/128), 256, 0, stream>>>(
      Xbf, Winbf, b_in, nullptr, Qb, Kbf, Vb, MROWS, 3*EMB, EMB);

  k_transposeV<<<dim3(SEQ/64, BH), 256, 0, stream>>>(Vb, Vt);

  k_attn5<<<1024, 512, 0, stream>>>(Qb, Kbf, Vt, attnP, ctx);

  k_gemm_bt<0><<<dim3(EMB/128, MROWS/128), 256, 0, stream>>>(
      ctx, Woutbf, b_out, out, nullptr, nullptr, nullptr, MROWS, EMB, EMB);
}